// Round 2
// baseline (1049.912 us; speedup 1.0000x reference)
//
#include <hip/hip_runtime.h>

#define NCLASSES 6
#define NGRAPHS 16
#define BN_EPS 1e-5f

// ---------------- BN-fold: W'[l][mat][k][d] = W[l][k][d]*scale(l,mat,d);
// shift[l][mat][d] = be + (b - m)*scale ----------------
__global__ void k_fold(const float* __restrict__ W1, const float* __restrict__ b1,
                       const float* __restrict__ g1, const float* __restrict__ be1,
                       const float* __restrict__ m1, const float* __restrict__ v1,
                       const float* __restrict__ W2, const float* __restrict__ b2,
                       const float* __restrict__ g2, const float* __restrict__ be2,
                       const float* __restrict__ m2, const float* __restrict__ v2,
                       float* __restrict__ Wf, float* __restrict__ Sf) {
  int idx = blockIdx.x * blockDim.x + threadIdx.x;
  if (idx >= 3 * 2 * 64 * 64) return;
  int d = idx & 63;
  int k = (idx >> 6) & 63;
  int mat = (idx >> 12) & 1;
  int l = idx >> 13;
  const float* W = mat ? W2 : W1;
  const float* b = mat ? b2 : b1;
  const float* g = mat ? g2 : g1;
  const float* be = mat ? be2 : be1;
  const float* m = mat ? m2 : m1;
  const float* v = mat ? v2 : v1;
  float scale = g[l * 64 + d] * rsqrtf(v[l * 64 + d] + BN_EPS);
  Wf[idx] = W[(l * 64 + k) * 64 + d] * scale;
  if (k == 0)
    Sf[(l * 2 + mat) * 64 + d] = be[l * 64 + d] + (b[l * 64 + d] - m[l * 64 + d]) * scale;
}

// ---------------- CSR build ----------------
__global__ void k_deg(const int* __restrict__ dst, int nE, int* __restrict__ deg) {
  int e = blockIdx.x * blockDim.x + threadIdx.x;
  if (e < nE) atomicAdd(&deg[dst[e]], 1);
}

// single-block exclusive scan; deg is read and replaced by cursor (== offs copy)
__global__ __launch_bounds__(1024) void k_scan(int* __restrict__ degcur,
                                               int* __restrict__ offs, int n) {
  __shared__ int part[1024];
  int t = threadIdx.x;
  int chunk = (n + 1023) >> 10;
  int i0 = t * chunk;
  int i1 = min(i0 + chunk, n);
  int s = 0;
  for (int i = i0; i < i1; ++i) s += degcur[i];
  part[t] = s;
  __syncthreads();
  int val = s;
  for (int off = 1; off < 1024; off <<= 1) {
    int tmp = (t >= off) ? part[t - off] : 0;
    __syncthreads();
    val += tmp;
    part[t] = val;
    __syncthreads();
  }
  int run = val - s;  // exclusive prefix for this thread's chunk
  for (int i = i0; i < i1; ++i) {
    int dg = degcur[i];
    offs[i] = run;
    degcur[i] = run;  // cursor init
    run += dg;
  }
  if (t == 1023) offs[n] = part[1023];
}

__global__ void k_fill(const int* __restrict__ src, const int* __restrict__ dstA, int nE,
                       int* __restrict__ cursor, int* __restrict__ csr_src) {
  int e = blockIdx.x * blockDim.x + threadIdx.x;
  if (e < nE) {
    int pos = atomicAdd(&cursor[dstA[e]], 1);
    csr_src[pos] = src[e];
  }
}

// ---------------- fused GIN layer: z = h + sum_neigh(h); h' = relu(bn2(relu(bn1(z@W1))@W2))
// one wave per node; lane d owns output feature d; weight columns in VGPRs ----------------
__global__ __launch_bounds__(256) void k_layer(
    const float* __restrict__ h_in, float* __restrict__ h_out,
    const int* __restrict__ offs, const int* __restrict__ csr_src,
    const float* __restrict__ Wf, const float* __restrict__ Sf, int n) {
  __shared__ __align__(16) float zbuf[4][64];
  const int lane = threadIdx.x & 63;
  const int wslot = threadIdx.x >> 6;

  float w1[64], w2[64];
#pragma unroll
  for (int k = 0; k < 64; ++k) {
    w1[k] = Wf[k * 64 + lane];
    w2[k] = Wf[4096 + k * 64 + lane];
  }
  const float s1 = Sf[lane];
  const float s2 = Sf[64 + lane];

  int wave = blockIdx.x * 4 + wslot;
  int nwaves = gridDim.x * 4;
  for (int node = wave; node < n; node += nwaves) {
    // gather: self + in-neighbors (atomic-free via CSR)
    float acc = h_in[node * 64 + lane];
    int e0 = offs[node], e1 = offs[node + 1];
    int e = e0;
    float a0 = 0.f, a1 = 0.f, a2 = 0.f, a3 = 0.f;
    for (; e + 3 < e1; e += 4) {
      int q0 = csr_src[e], q1 = csr_src[e + 1], q2 = csr_src[e + 2], q3 = csr_src[e + 3];
      a0 += h_in[q0 * 64 + lane];
      a1 += h_in[q1 * 64 + lane];
      a2 += h_in[q2 * 64 + lane];
      a3 += h_in[q3 * 64 + lane];
    }
    for (; e < e1; ++e) a0 += h_in[csr_src[e] * 64 + lane];
    acc += (a0 + a1) + (a2 + a3);

    // broadcast z through per-wave LDS slot (wave-synchronous; no __syncthreads)
    zbuf[wslot][lane] = acc;
    asm volatile("s_waitcnt lgkmcnt(0)" ::: "memory");

    float p0 = s1, p1 = 0.f, p2 = 0.f, p3 = 0.f;
#pragma unroll
    for (int k0 = 0; k0 < 64; k0 += 4) {
      float4 z4 = *reinterpret_cast<const float4*>(&zbuf[wslot][k0]);
      p0 = fmaf(z4.x, w1[k0 + 0], p0);
      p1 = fmaf(z4.y, w1[k0 + 1], p1);
      p2 = fmaf(z4.z, w1[k0 + 2], p2);
      p3 = fmaf(z4.w, w1[k0 + 3], p3);
    }
    float o1 = fmaxf((p0 + p1) + (p2 + p3), 0.f);

    asm volatile("" ::: "memory");
    zbuf[wslot][lane] = o1;
    asm volatile("s_waitcnt lgkmcnt(0)" ::: "memory");

    float q0 = s2, q1 = 0.f, q2 = 0.f, q3 = 0.f;
#pragma unroll
    for (int k0 = 0; k0 < 64; k0 += 4) {
      float4 z4 = *reinterpret_cast<const float4*>(&zbuf[wslot][k0]);
      q0 = fmaf(z4.x, w2[k0 + 0], q0);
      q1 = fmaf(z4.y, w2[k0 + 1], q1);
      q2 = fmaf(z4.z, w2[k0 + 2], q2);
      q3 = fmaf(z4.w, w2[k0 + 3], q3);
    }
    h_out[node * 64 + lane] = fmaxf((q0 + q1) + (q2 + q3), 0.f);
    asm volatile("" ::: "memory");
  }
}

// ---------------- pooling: block-local LDS accumulation then global atomics ----------------
__global__ __launch_bounds__(256) void k_pool(const float* __restrict__ h,
                                              const int* __restrict__ batch, int n,
                                              float* __restrict__ gsum,
                                              float* __restrict__ gcnt) {
  __shared__ float lsum[NGRAPHS * 64];
  __shared__ float lcnt[NGRAPHS];
  for (int i = threadIdx.x; i < NGRAPHS * 64; i += 256) lsum[i] = 0.f;
  if (threadIdx.x < NGRAPHS) lcnt[threadIdx.x] = 0.f;
  __syncthreads();
  int lane = threadIdx.x & 63, wslot = threadIdx.x >> 6;
  int wave = blockIdx.x * 4 + wslot, nw = gridDim.x * 4;
  for (int node = wave; node < n; node += nw) {
    int g = batch[node];
    atomicAdd(&lsum[g * 64 + lane], h[node * 64 + lane]);
    if (lane == 0) atomicAdd(&lcnt[g], 1.f);
  }
  __syncthreads();
  for (int i = threadIdx.x; i < NGRAPHS * 64; i += 256) atomicAdd(&gsum[i], lsum[i]);
  if (threadIdx.x < NGRAPHS) atomicAdd(&gcnt[threadIdx.x], lcnt[threadIdx.x]);
}

// ---------------- heads: pooled@wp+bp, pooled@ws+bs ----------------
__global__ void k_head(const float* __restrict__ gsum, const float* __restrict__ gcnt,
                       const float* __restrict__ wp, const float* __restrict__ bp,
                       const float* __restrict__ wsec, const float* __restrict__ bsec,
                       float* __restrict__ out) {
  int t = threadIdx.x;
  if (t >= NGRAPHS * NCLASSES) return;
  int g = t / NCLASSES, c = t % NCLASSES;
  float inv = 1.f / fmaxf(gcnt[g], 1.f);
  float p = 0.f, s = 0.f;
  for (int d = 0; d < 64; ++d) {
    float pd = gsum[g * 64 + d] * inv;
    p = fmaf(pd, wp[d * NCLASSES + c], p);
    s = fmaf(pd, wsec[d * NCLASSES + c], s);
  }
  out[t] = p + bp[c];
  out[NGRAPHS * NCLASSES + t] = s + bsec[c];
}

extern "C" void kernel_launch(void* const* d_in, const int* in_sizes, int n_in,
                              void* d_out, int out_size, void* d_ws, size_t ws_size,
                              hipStream_t stream) {
  const float* x = (const float*)d_in[0];
  const int* ei = (const int*)d_in[1];
  const int* batch = (const int*)d_in[2];
  const float* W1 = (const float*)d_in[3];
  const float* b1 = (const float*)d_in[4];
  const float* g1 = (const float*)d_in[5];
  const float* be1 = (const float*)d_in[6];
  const float* m1 = (const float*)d_in[7];
  const float* v1 = (const float*)d_in[8];
  const float* W2 = (const float*)d_in[9];
  const float* b2 = (const float*)d_in[10];
  const float* g2 = (const float*)d_in[11];
  const float* be2 = (const float*)d_in[12];
  const float* m2 = (const float*)d_in[13];
  const float* v2 = (const float*)d_in[14];
  const float* wp = (const float*)d_in[15];
  const float* bp = (const float*)d_in[16];
  const float* wsec = (const float*)d_in[17];
  const float* bsec = (const float*)d_in[18];

  const int nE = in_sizes[1] / 2;
  const int n = in_sizes[0] / 64;

  char* p = (char*)d_ws;
  auto alloc = [&](size_t bytes) {
    char* r = p;
    p += (bytes + 255) & ~(size_t)255;
    return r;
  };
  float* hA = (float*)alloc((size_t)n * 64 * 4);
  float* hB = (float*)alloc((size_t)n * 64 * 4);
  int* csr = (int*)alloc((size_t)nE * 4);
  int* offs = (int*)alloc((size_t)(n + 1) * 4);
  int* cursor = (int*)alloc((size_t)n * 4);
  float* Wf = (float*)alloc(3 * 2 * 64 * 64 * 4);
  float* Sf = (float*)alloc(3 * 2 * 64 * 4);
  float* gsum = (float*)alloc(NGRAPHS * 64 * 4);
  float* gcnt = (float*)alloc(NGRAPHS * 4);

  hipMemsetAsync(cursor, 0, (size_t)n * 4, stream);
  hipMemsetAsync(gsum, 0, NGRAPHS * 64 * 4, stream);
  hipMemsetAsync(gcnt, 0, NGRAPHS * 4, stream);

  k_fold<<<(3 * 2 * 64 * 64 + 255) / 256, 256, 0, stream>>>(
      W1, b1, g1, be1, m1, v1, W2, b2, g2, be2, m2, v2, Wf, Sf);
  k_deg<<<(nE + 255) / 256, 256, 0, stream>>>(ei + nE, nE, cursor);
  k_scan<<<1, 1024, 0, stream>>>(cursor, offs, n);
  k_fill<<<(nE + 255) / 256, 256, 0, stream>>>(ei, ei + nE, nE, cursor, csr);

  const int LAYER_BLOCKS = 2048;
  k_layer<<<LAYER_BLOCKS, 256, 0, stream>>>(x, hA, offs, csr, Wf + 0 * 8192, Sf + 0 * 128, n);
  k_layer<<<LAYER_BLOCKS, 256, 0, stream>>>(hA, hB, offs, csr, Wf + 1 * 8192, Sf + 1 * 128, n);
  k_layer<<<LAYER_BLOCKS, 256, 0, stream>>>(hB, hA, offs, csr, Wf + 2 * 8192, Sf + 2 * 128, n);

  k_pool<<<512, 256, 0, stream>>>(hA, batch, n, gsum, gcnt);
  k_head<<<1, 128, 0, stream>>>(gsum, gcnt, wp, bp, wsec, bsec, (float*)d_out);
}

// Round 3
// 832.496 us; speedup vs baseline: 1.2612x; 1.2612x over previous
//
#include <hip/hip_runtime.h>

#define NCLASSES 6
#define NGRAPHS 16
#define BN_EPS 1e-5f
#define SCAN_BLOCK 256
#define SCAN_ITEMS 16  // 4096 elements per block

// ---------------- BN-fold: W'[l][mat][k][d] = W[l][k][d]*scale(l,mat,d);
// shift[l][mat][d] = be + (b - m)*scale ----------------
__global__ void k_fold(const float* __restrict__ W1, const float* __restrict__ b1,
                       const float* __restrict__ g1, const float* __restrict__ be1,
                       const float* __restrict__ m1, const float* __restrict__ v1,
                       const float* __restrict__ W2, const float* __restrict__ b2,
                       const float* __restrict__ g2, const float* __restrict__ be2,
                       const float* __restrict__ m2, const float* __restrict__ v2,
                       float* __restrict__ Wf, float* __restrict__ Sf) {
  int idx = blockIdx.x * blockDim.x + threadIdx.x;
  if (idx >= 3 * 2 * 64 * 64) return;
  int d = idx & 63;
  int k = (idx >> 6) & 63;
  int mat = (idx >> 12) & 1;
  int l = idx >> 13;
  const float* W = mat ? W2 : W1;
  const float* b = mat ? b2 : b1;
  const float* g = mat ? g2 : g1;
  const float* be = mat ? be2 : be1;
  const float* m = mat ? m2 : m1;
  const float* v = mat ? v2 : v1;
  float scale = g[l * 64 + d] * rsqrtf(v[l * 64 + d] + BN_EPS);
  Wf[idx] = W[(l * 64 + k) * 64 + d] * scale;
  if (k == 0)
    Sf[(l * 2 + mat) * 64 + d] = be[l * 64 + d] + (b[l * 64 + d] - m[l * 64 + d]) * scale;
}

// ---------------- CSR build ----------------
__global__ void k_deg(const int* __restrict__ dst, int nE, int* __restrict__ deg) {
  int e = blockIdx.x * blockDim.x + threadIdx.x;
  if (e < nE) atomicAdd(&deg[dst[e]], 1);
}

// pass 1: per-block (4096-chunk) sums
__global__ __launch_bounds__(SCAN_BLOCK) void k_scan_partial(
    const int* __restrict__ deg, int n, int* __restrict__ partials) {
  __shared__ int lds[SCAN_BLOCK];
  int t = threadIdx.x;
  int base = blockIdx.x * SCAN_BLOCK * SCAN_ITEMS + t * SCAN_ITEMS;
  int s = 0;
#pragma unroll
  for (int i = 0; i < SCAN_ITEMS; ++i) {
    int idx = base + i;
    if (idx < n) s += deg[idx];
  }
  lds[t] = s;
  __syncthreads();
  for (int off = SCAN_BLOCK / 2; off > 0; off >>= 1) {
    if (t < off) lds[t] += lds[t + off];
    __syncthreads();
  }
  if (t == 0) partials[blockIdx.x] = lds[0];
}

// pass 2: serial exclusive scan of block partials (nb ~ 25)
__global__ void k_scan_root(int* __restrict__ partials, int nb,
                            int* __restrict__ offs, int n) {
  if (threadIdx.x == 0) {
    int run = 0;
    for (int i = 0; i < nb; ++i) {
      int v = partials[i];
      partials[i] = run;
      run += v;
    }
    offs[n] = run;
  }
}

// pass 3: write exclusive offsets + cursor copy
__global__ __launch_bounds__(SCAN_BLOCK) void k_scan_write(
    const int* __restrict__ deg, int n, const int* __restrict__ partials,
    int* __restrict__ offs, int* __restrict__ cursor) {
  __shared__ int lds[SCAN_BLOCK];
  int t = threadIdx.x;
  int base = blockIdx.x * SCAN_BLOCK * SCAN_ITEMS + t * SCAN_ITEMS;
  int local[SCAN_ITEMS];
  int s = 0;
#pragma unroll
  for (int i = 0; i < SCAN_ITEMS; ++i) {
    int idx = base + i;
    int v = (idx < n) ? deg[idx] : 0;
    local[i] = v;
    s += v;
  }
  lds[t] = s;
  __syncthreads();
  int val = s;
  for (int off = 1; off < SCAN_BLOCK; off <<= 1) {
    int tmp = (t >= off) ? lds[t - off] : 0;
    __syncthreads();
    val += tmp;
    lds[t] = val;
    __syncthreads();
  }
  int run = partials[blockIdx.x] + val - s;  // exclusive prefix for this thread
#pragma unroll
  for (int i = 0; i < SCAN_ITEMS; ++i) {
    int idx = base + i;
    if (idx < n) {
      offs[idx] = run;
      cursor[idx] = run;
      run += local[i];
    }
  }
}

__global__ void k_fill(const int* __restrict__ src, const int* __restrict__ dstA, int nE,
                       int* __restrict__ cursor, int* __restrict__ csr_src) {
  int e = blockIdx.x * blockDim.x + threadIdx.x;
  if (e < nE) {
    int pos = atomicAdd(&cursor[dstA[e]], 1);
    csr_src[pos] = src[e];
  }
}

// ---------------- fused GIN layer: z = h + sum_neigh(h); h' = relu(bn2(relu(bn1(z@W1))@W2))
// one wave per node; lane d owns output feature d; weight columns in VGPRs ----------------
__global__ __launch_bounds__(256) void k_layer(
    const float* __restrict__ h_in, float* __restrict__ h_out,
    const int* __restrict__ offs, const int* __restrict__ csr_src,
    const float* __restrict__ Wf, const float* __restrict__ Sf, int n) {
  __shared__ __align__(16) float zbuf[4][64];
  const int lane = threadIdx.x & 63;
  const int wslot = threadIdx.x >> 6;

  float w1[64], w2[64];
#pragma unroll
  for (int k = 0; k < 64; ++k) {
    w1[k] = Wf[k * 64 + lane];
    w2[k] = Wf[4096 + k * 64 + lane];
  }
  const float s1 = Sf[lane];
  const float s2 = Sf[64 + lane];

  int wave = blockIdx.x * 4 + wslot;
  int nwaves = gridDim.x * 4;
  for (int node = wave; node < n; node += nwaves) {
    // gather: self + in-neighbors (atomic-free via CSR)
    float acc = h_in[node * 64 + lane];
    int e0 = offs[node], e1 = offs[node + 1];
    int e = e0;
    float a0 = 0.f, a1 = 0.f, a2 = 0.f, a3 = 0.f;
    for (; e + 3 < e1; e += 4) {
      int q0 = csr_src[e], q1 = csr_src[e + 1], q2 = csr_src[e + 2], q3 = csr_src[e + 3];
      a0 += h_in[q0 * 64 + lane];
      a1 += h_in[q1 * 64 + lane];
      a2 += h_in[q2 * 64 + lane];
      a3 += h_in[q3 * 64 + lane];
    }
    for (; e < e1; ++e) a0 += h_in[csr_src[e] * 64 + lane];
    acc += (a0 + a1) + (a2 + a3);

    // broadcast z through per-wave LDS slot (wave-synchronous; no __syncthreads)
    zbuf[wslot][lane] = acc;
    asm volatile("s_waitcnt lgkmcnt(0)" ::: "memory");

    float p0 = s1, p1 = 0.f, p2 = 0.f, p3 = 0.f;
#pragma unroll
    for (int k0 = 0; k0 < 64; k0 += 4) {
      float4 z4 = *reinterpret_cast<const float4*>(&zbuf[wslot][k0]);
      p0 = fmaf(z4.x, w1[k0 + 0], p0);
      p1 = fmaf(z4.y, w1[k0 + 1], p1);
      p2 = fmaf(z4.z, w1[k0 + 2], p2);
      p3 = fmaf(z4.w, w1[k0 + 3], p3);
    }
    float o1 = fmaxf((p0 + p1) + (p2 + p3), 0.f);

    asm volatile("" ::: "memory");
    zbuf[wslot][lane] = o1;
    asm volatile("s_waitcnt lgkmcnt(0)" ::: "memory");

    float q0 = s2, q1 = 0.f, q2 = 0.f, q3 = 0.f;
#pragma unroll
    for (int k0 = 0; k0 < 64; k0 += 4) {
      float4 z4 = *reinterpret_cast<const float4*>(&zbuf[wslot][k0]);
      q0 = fmaf(z4.x, w2[k0 + 0], q0);
      q1 = fmaf(z4.y, w2[k0 + 1], q1);
      q2 = fmaf(z4.z, w2[k0 + 2], q2);
      q3 = fmaf(z4.w, w2[k0 + 3], q3);
    }
    h_out[node * 64 + lane] = fmaxf((q0 + q1) + (q2 + q3), 0.f);
    asm volatile("" ::: "memory");
  }
}

// ---------------- pooling: block-local LDS accumulation then global atomics ----------------
__global__ __launch_bounds__(256) void k_pool(const float* __restrict__ h,
                                              const int* __restrict__ batch, int n,
                                              float* __restrict__ gsum,
                                              float* __restrict__ gcnt) {
  __shared__ float lsum[NGRAPHS * 64];
  __shared__ float lcnt[NGRAPHS];
  for (int i = threadIdx.x; i < NGRAPHS * 64; i += 256) lsum[i] = 0.f;
  if (threadIdx.x < NGRAPHS) lcnt[threadIdx.x] = 0.f;
  __syncthreads();
  int lane = threadIdx.x & 63, wslot = threadIdx.x >> 6;
  int wave = blockIdx.x * 4 + wslot, nw = gridDim.x * 4;
  for (int node = wave; node < n; node += nw) {
    int g = batch[node];
    atomicAdd(&lsum[g * 64 + lane], h[node * 64 + lane]);
    if (lane == 0) atomicAdd(&lcnt[g], 1.f);
  }
  __syncthreads();
  for (int i = threadIdx.x; i < NGRAPHS * 64; i += 256) atomicAdd(&gsum[i], lsum[i]);
  if (threadIdx.x < NGRAPHS) atomicAdd(&gcnt[threadIdx.x], lcnt[threadIdx.x]);
}

// ---------------- heads: pooled@wp+bp, pooled@ws+bs ----------------
__global__ void k_head(const float* __restrict__ gsum, const float* __restrict__ gcnt,
                       const float* __restrict__ wp, const float* __restrict__ bp,
                       const float* __restrict__ wsec, const float* __restrict__ bsec,
                       float* __restrict__ out) {
  int t = threadIdx.x;
  if (t >= NGRAPHS * NCLASSES) return;
  int g = t / NCLASSES, c = t % NCLASSES;
  float inv = 1.f / fmaxf(gcnt[g], 1.f);
  float p = 0.f, s = 0.f;
  for (int d = 0; d < 64; ++d) {
    float pd = gsum[g * 64 + d] * inv;
    p = fmaf(pd, wp[d * NCLASSES + c], p);
    s = fmaf(pd, wsec[d * NCLASSES + c], s);
  }
  out[t] = p + bp[c];
  out[NGRAPHS * NCLASSES + t] = s + bsec[c];
}

extern "C" void kernel_launch(void* const* d_in, const int* in_sizes, int n_in,
                              void* d_out, int out_size, void* d_ws, size_t ws_size,
                              hipStream_t stream) {
  const float* x = (const float*)d_in[0];
  const int* ei = (const int*)d_in[1];
  const int* batch = (const int*)d_in[2];
  const float* W1 = (const float*)d_in[3];
  const float* b1 = (const float*)d_in[4];
  const float* g1 = (const float*)d_in[5];
  const float* be1 = (const float*)d_in[6];
  const float* m1 = (const float*)d_in[7];
  const float* v1 = (const float*)d_in[8];
  const float* W2 = (const float*)d_in[9];
  const float* b2 = (const float*)d_in[10];
  const float* g2 = (const float*)d_in[11];
  const float* be2 = (const float*)d_in[12];
  const float* m2 = (const float*)d_in[13];
  const float* v2 = (const float*)d_in[14];
  const float* wp = (const float*)d_in[15];
  const float* bp = (const float*)d_in[16];
  const float* wsec = (const float*)d_in[17];
  const float* bsec = (const float*)d_in[18];

  const int nE = in_sizes[1] / 2;
  const int n = in_sizes[0] / 64;

  char* p = (char*)d_ws;
  auto alloc = [&](size_t bytes) {
    char* r = p;
    p += (bytes + 255) & ~(size_t)255;
    return r;
  };
  float* hA = (float*)alloc((size_t)n * 64 * 4);
  float* hB = (float*)alloc((size_t)n * 64 * 4);
  int* csr = (int*)alloc((size_t)nE * 4);
  int* offs = (int*)alloc((size_t)(n + 1) * 4);
  int* cursor = (int*)alloc((size_t)n * 4);
  int* deg = (int*)alloc((size_t)n * 4);
  int* partials = (int*)alloc(1024 * 4);
  float* Wf = (float*)alloc(3 * 2 * 64 * 64 * 4);
  float* Sf = (float*)alloc(3 * 2 * 64 * 4);
  float* gsum = (float*)alloc(NGRAPHS * 64 * 4);
  float* gcnt = (float*)alloc(NGRAPHS * 4);

  hipMemsetAsync(deg, 0, (size_t)n * 4, stream);
  hipMemsetAsync(gsum, 0, NGRAPHS * 64 * 4, stream);
  hipMemsetAsync(gcnt, 0, NGRAPHS * 4, stream);

  k_fold<<<(3 * 2 * 64 * 64 + 255) / 256, 256, 0, stream>>>(
      W1, b1, g1, be1, m1, v1, W2, b2, g2, be2, m2, v2, Wf, Sf);
  k_deg<<<(nE + 255) / 256, 256, 0, stream>>>(ei + nE, nE, deg);

  const int nb = (n + SCAN_BLOCK * SCAN_ITEMS - 1) / (SCAN_BLOCK * SCAN_ITEMS);
  k_scan_partial<<<nb, SCAN_BLOCK, 0, stream>>>(deg, n, partials);
  k_scan_root<<<1, 64, 0, stream>>>(partials, nb, offs, n);
  k_scan_write<<<nb, SCAN_BLOCK, 0, stream>>>(deg, n, partials, offs, cursor);

  k_fill<<<(nE + 255) / 256, 256, 0, stream>>>(ei, ei + nE, nE, cursor, csr);

  const int LAYER_BLOCKS = 2048;
  k_layer<<<LAYER_BLOCKS, 256, 0, stream>>>(x, hA, offs, csr, Wf + 0 * 8192, Sf + 0 * 128, n);
  k_layer<<<LAYER_BLOCKS, 256, 0, stream>>>(hA, hB, offs, csr, Wf + 1 * 8192, Sf + 1 * 128, n);
  k_layer<<<LAYER_BLOCKS, 256, 0, stream>>>(hB, hA, offs, csr, Wf + 2 * 8192, Sf + 2 * 128, n);

  k_pool<<<512, 256, 0, stream>>>(hA, batch, n, gsum, gcnt);
  k_head<<<1, 128, 0, stream>>>(gsum, gcnt, wp, bp, wsec, bsec, (float*)d_out);
}